// Round 17
// baseline (104.947 us; speedup 1.0000x reference)
//
#include <hip/hip_runtime.h>
#include <math.h>

// NeRF renderer: 4096 rays, 128+128 samples, tiny MLP field.
// ONE WAVE = ONE RAY = ONE BLOCK (64 threads). ALL THREE layers on the matrix
// pipe (L1 K=4-padded, L2 bias-in-C, head), unit-permutation trick so each
// MFMA's D layout IS the next MFMA's B-fragment layout (verified R13/R14/R16).
// R17: block size 256->64. Since R14 the kernel has no __syncthreads (LDS is
// wave-private, weights in registers), so 4-wave blocks were pure packaging
// that capped occupancy at 4 waves/SIMD (grid 1024 on 256 CUs). 64-thread
// blocks -> ~6.5 KB LDS/block -> 24 blocks/CU -> 6 waves/SIMD (1.5x TLP) to
// fill the dependency stalls behind R14's 57% VALUBusy + 13% MfmaUtil.
//
// Spill discipline (R2..R8): no __launch_bounds__ min-waves arg. No dynamic
// indexing of private arrays. hbm_bytes <2 MB == clean; VGPR <=102 keeps
// >=5 waves/SIMD.

#define BOUNDF 2.0f

typedef _Float16 f16;
typedef f16 f16x2 __attribute__((ext_vector_type(2)));
typedef f16 f16x8 __attribute__((ext_vector_type(8)));
typedef float f32x4 __attribute__((ext_vector_type(4)));

union U16 { f16x8 v8; f16x2 v2[4]; };

struct RayLds {
    float zc[128];
    float zf[128];
    float sgc[128];
    float sgf[128];
    float rgbc[128][3];
    float rgbf[128][3];
    float cdf[128];       // cdf+scr double as the 256-float epilogue stage
    float scr[128];       //   (must stay adjacent & 16B-aligned)
    unsigned short perm[256];
};

__device__ __forceinline__ f32x4 mfma16(f16x8 a, f16x8 b, f32x4 c) {
    return __builtin_amdgcn_mfma_f32_16x16x32_f16(a, b, c, 0, 0, 0);
}

__device__ __forceinline__ f16x2 pkrtz(float a, float b) {
    return __builtin_bit_cast(f16x2, __builtin_amdgcn_cvt_pkrtz(a, b));
}

__device__ __forceinline__ f16x2 relu_cvt(float a, float b) {
    return pkrtz(fmaxf(a, 0.0f), fmaxf(b, 0.0f));
}

__device__ __forceinline__ float scan_incl_mul(float p, int lane) {
#pragma unroll
    for (int off = 1; off < 64; off <<= 1) {
        float t = __shfl_up(p, off, 64);
        if (lane >= off) p *= t;
    }
    return p;
}

__device__ __forceinline__ float scan_incl_add(float p, int lane) {
#pragma unroll
    for (int off = 1; off < 64; off <<= 1) {
        float t = __shfl_up(p, off, 64);
        if (lane >= off) p += t;
    }
    return p;
}

// One field pass (128 samples) for one ray/wave, via triple MFMA.
template<bool COARSE>
__device__ __forceinline__ void field_pass(
    RayLds& R,
    f16x8 w1a0, f16x8 w1a1, f16x8 w1a2, f16x8 w1a3,
    f16x8 b00, f16x8 b01, f16x8 b10, f16x8 b11,
    f16x8 b20, f16x8 b21, f16x8 b30, f16x8 b31,
    f16x8 hda0, f16x8 hda1,
    f32x4 b2q0, f32x4 b2q1, f32x4 b2q2, f32x4 b2q3,
    float ox, float oy, float oz, float dx, float dy, float dzv,
    float nearv, float span, float base_r, float base_g, float base_b, int lane)
{
    const int ms = lane & 15;          // sample-within-tile
    f32x4* stage = (f32x4*)(&R.cdf[0]);   // 256 floats: cdf+scr (idle here)
    const f32x4 zero = {0.f, 0.f, 0.f, 0.f};
#pragma unroll 1
    for (int Mtb = 0; Mtb < 2; ++Mtb) {
#pragma unroll 2
        for (int Mti = 0; Mti < 4; ++Mti) {
            int m = Mtb * 64 + Mti * 16 + ms;
            float z = COARSE ? fmaf(span, (float)m * (1.0f / 127.0f), nearv) : R.zf[m];
            float px = fminf(fmaxf(fmaf(dx, z, ox), -BOUNDF), BOUNDF);
            float py = fminf(fmaxf(fmaf(dy, z, oy), -BOUNDF), BOUNDF);
            float pz = fminf(fmaxf(fmaf(dzv, z, oz), -BOUNDF), BOUNDF);

            // P B-fragment (packed cvt): only k=0..3 on quad0 matter
            U16 up;
            up.v2[0] = pkrtz(px, py);
            up.v2[1] = pkrtz(pz, 1.0f);
            up.v2[2] = f16x2{(f16)0.f, (f16)0.f};
            up.v2[3] = f16x2{(f16)0.f, (f16)0.f};
            f16x8 pf = up.v8;

            // layer-1 MFMA: hacc_nt[r] = h1pre[phys (nt,quad,r)][ms]
            f32x4 hacc0 = mfma16(w1a0, pf, zero);
            f32x4 hacc1 = mfma16(w1a1, pf, zero);
            f32x4 hacc2 = mfma16(w1a2, pf, zero);
            f32x4 hacc3 = mfma16(w1a3, pf, zero);

            // relu + packed cvt: physical layout IS the L2 B-fragment layout
            U16 u0, u1;
            u0.v2[0] = relu_cvt(hacc0[0], hacc0[1]);
            u0.v2[1] = relu_cvt(hacc0[2], hacc0[3]);
            u0.v2[2] = relu_cvt(hacc1[0], hacc1[1]);
            u0.v2[3] = relu_cvt(hacc1[2], hacc1[3]);
            u1.v2[0] = relu_cvt(hacc2[0], hacc2[1]);
            u1.v2[1] = relu_cvt(hacc2[2], hacc2[3]);
            u1.v2[2] = relu_cvt(hacc3[0], hacc3[1]);
            u1.v2[3] = relu_cvt(hacc3[2], hacc3[3]);
            f16x8 hf0 = u0.v8, hf1 = u1.v8;

            // layer-2 MFMA (bias in C): acc_nt[r] = h2[phys (nt,quad,r)][ms]
            f32x4 acc0 = mfma16(b01, hf1, mfma16(b00, hf0, b2q0));
            f32x4 acc1 = mfma16(b11, hf1, mfma16(b10, hf0, b2q1));
            f32x4 acc2 = mfma16(b21, hf1, mfma16(b20, hf0, b2q2));
            f32x4 acc3 = mfma16(b31, hf1, mfma16(b30, hf0, b2q3));

            // relu + packed cvt: physical layout IS the head B-fragment layout
            U16 v0, v1;
            v0.v2[0] = relu_cvt(acc0[0], acc0[1]);
            v0.v2[1] = relu_cvt(acc0[2], acc0[3]);
            v0.v2[2] = relu_cvt(acc1[0], acc1[1]);
            v0.v2[3] = relu_cvt(acc1[2], acc1[3]);
            v1.v2[0] = relu_cvt(acc2[0], acc2[1]);
            v1.v2[1] = relu_cvt(acc2[2], acc2[3]);
            v1.v2[2] = relu_cvt(acc3[0], acc3[1]);
            v1.v2[3] = relu_cvt(acc3[2], acc3[3]);
            f16x8 h0 = v0.v8, h1f = v1.v8;

            // head MFMA: D[o][s] -> lane (quad0, s) regs 0..3
            f32x4 tv = mfma16(hda1, h1f, mfma16(hda0, h0, zero));
            if (lane < 16) stage[Mti * 16 + ms] = tv;
        }
        // batched epilogue: each lane finishes one of the 64 staged samples
        {
            f32x4 tq = stage[lane];
            int m2 = Mtb * 64 + lane;
            float e  = __expf(-fabsf(tq[0]));
            float sg = fmaxf(tq[0], 0.0f) + __logf(1.0f + e);   // stable softplus
            float rr = __builtin_amdgcn_rcpf(1.0f + __expf(-(tq[1] + base_r)));
            float gg = __builtin_amdgcn_rcpf(1.0f + __expf(-(tq[2] + base_g)));
            float bb = __builtin_amdgcn_rcpf(1.0f + __expf(-(tq[3] + base_b)));
            if (COARSE) {
                R.sgc[m2] = sg;
                R.rgbc[m2][0] = rr; R.rgbc[m2][1] = gg; R.rgbc[m2][2] = bb;
            } else {
                R.sgf[m2] = sg;
                R.rgbf[m2][0] = rr; R.rgbf[m2][1] = gg; R.rgbf[m2][2] = bb;
            }
        }
    }
}

__global__ __launch_bounds__(64)
void nerf_kernel(const float* __restrict__ rays_o, const float* __restrict__ rays_d,
                 const float* __restrict__ W1, const float* __restrict__ b1,
                 const float* __restrict__ W2, const float* __restrict__ b2,
                 const float* __restrict__ Wsig, const float* __restrict__ Wrgb,
                 const float* __restrict__ brgb,
                 float* __restrict__ out_depth, float* __restrict__ out_img,
                 int nRays)
{
    __shared__ RayLds R;

    const int lane = threadIdx.x & 63;
    const int ms   = lane & 15;
    const int quad = lane >> 4;

    // --- W1 as 4 MFMA A-fragments (permuted units; only quad0 k=0..3 nonzero,
    //     b1 folded in at k=3 since P[3]=1) ---
    f16x8 w1a[4];
#pragma unroll
    for (int nt = 0; nt < 4; ++nt) {
        f16x8 t;
#pragma unroll
        for (int j = 0; j < 8; ++j) t[j] = (f16)0.f;
        if (quad == 0) {
            int u = 32 * (nt >> 1) + 8 * (ms >> 2) + 4 * (nt & 1) + (ms & 3);
            t[0] = (f16)W1[u];
            t[1] = (f16)W1[64 + u];
            t[2] = (f16)W1[128 + u];
            t[3] = (f16)b1[u];
        }
        w1a[nt] = t;
    }

    // --- W2 as 8 MFMA fragments with PERMUTED unit columns (byte-identical
    //     to verified R13/R14/R16) ---
    const int colbase = 8 * (ms >> 2) + (ms & 3);
    f16x8 b00, b01, b10, b11, b20, b21, b30, b31;
#pragma unroll
    for (int j = 0; j < 8; ++j) {
        int k0 = (quad * 8 + j) * 64;
        int k1 = (32 + quad * 8 + j) * 64;
        b00[j] = (f16)W2[k0 + colbase];      b01[j] = (f16)W2[k1 + colbase];
        b10[j] = (f16)W2[k0 + colbase + 4];  b11[j] = (f16)W2[k1 + colbase + 4];
        b20[j] = (f16)W2[k0 + colbase + 32]; b21[j] = (f16)W2[k1 + colbase + 32];
        b30[j] = (f16)W2[k0 + colbase + 36]; b31[j] = (f16)W2[k1 + colbase + 36];
    }
    // b2 as C-operand vectors, same permutation
    f32x4 b2q0, b2q1, b2q2, b2q3;
#pragma unroll
    for (int r = 0; r < 4; ++r) {
        b2q0[r] = b2[8 * quad + r];
        b2q1[r] = b2[8 * quad + 4 + r];
        b2q2[r] = b2[32 + 8 * quad + r];
        b2q3[r] = b2[32 + 8 * quad + 4 + r];
    }
    // head weight A-fragments (rows 4..15 garbage-but-unread)
    f16x8 hda0, hda1;
    {
        int msel = ms & 3;
#pragma unroll
        for (int j = 0; j < 8; ++j) {
            int u0 = quad * 8 + j, u1 = 32 + quad * 8 + j;
            float w0 = (msel == 0) ? Wsig[u0] : Wrgb[u0 * 3 + msel - 1];
            float w1 = (msel == 0) ? Wsig[u1] : Wrgb[u1 * 3 + msel - 1];
            hda0[j] = (f16)w0;
            hda1[j] = (f16)w1;
        }
    }

    int ray = blockIdx.x;
    bool valid = ray < nRays;
    int rayc = valid ? ray : (nRays - 1);

    const float ox = rays_o[rayc * 3 + 0], oy = rays_o[rayc * 3 + 1], oz = rays_o[rayc * 3 + 2];
    const float dx = rays_d[rayc * 3 + 0], dy = rays_d[rayc * 3 + 1], dzv = rays_d[rayc * 3 + 2];

    // --- near/far vs cube [-2,2]^3 ---
    float t0x = (-BOUNDF - ox) / (dx + 1e-15f), t1x = (BOUNDF - ox) / (dx + 1e-15f);
    float t0y = (-BOUNDF - oy) / (dy + 1e-15f), t1y = (BOUNDF - oy) / (dy + 1e-15f);
    float t0z = (-BOUNDF - oz) / (dzv + 1e-15f), t1z = (BOUNDF - oz) / (dzv + 1e-15f);
    float nearv = fmaxf(fminf(t0x, t1x), fmaxf(fminf(t0y, t1y), fminf(t0z, t1z)));
    float farv  = fminf(fmaxf(t0x, t1x), fminf(fmaxf(t0y, t1y), fmaxf(t0z, t1z)));
    if (farv < nearv) { nearv = 1e9f; farv = 1e9f; }
    nearv = fmaxf(nearv, 0.05f);
    const float span = farv - nearv;
    const float dzc = span * (1.0f / 127.0f);
    const float sample_dist = span * (1.0f / 128.0f);

    const float base_r = brgb[0] + dx * Wrgb[64 * 3 + 0] + dy * Wrgb[65 * 3 + 0] + dzv * Wrgb[66 * 3 + 0];
    const float base_g = brgb[1] + dx * Wrgb[64 * 3 + 1] + dy * Wrgb[65 * 3 + 1] + dzv * Wrgb[66 * 3 + 1];
    const float base_b = brgb[2] + dx * Wrgb[64 * 3 + 2] + dy * Wrgb[65 * 3 + 2] + dzv * Wrgb[66 * 3 + 2];

    const int s0 = lane, s1 = lane + 64;

    // z_vals
    R.zc[s0] = fmaf(span, (float)s0 * (1.0f / 127.0f), nearv);
    R.zc[s1] = fmaf(span, (float)s1 * (1.0f / 127.0f), nearv);

    // --- coarse field pass (triple MFMA) ---
    field_pass<true>(R, w1a[0], w1a[1], w1a[2], w1a[3],
                     b00, b01, b10, b11, b20, b21, b30, b31,
                     hda0, hda1, b2q0, b2q1, b2q2, b2q3,
                     ox, oy, oz, dx, dy, dzv, nearv, span, base_r, base_g, base_b, lane);

    // --- coarse alphas ---
    {
        float zA = R.zc[s0], zB = R.zc[s1];
        float dA = R.zc[s0 + 1] - zA;
        float dB = (s1 < 127) ? (R.zc[s1 + 1] - zB) : sample_dist;
        R.scr[s0] = 1.0f - __expf(-dA * R.sgc[s0]);
        R.scr[s1] = 1.0f - __expf(-dB * R.sgc[s1]);
    }

    // --- wave-parallel cumprod: weights for elements 2l, 2l+1 ---
    {
        float aa = R.scr[2 * lane], ab = R.scr[2 * lane + 1];
        float ma = 1.0f - aa + 1e-15f, mb = 1.0f - ab + 1e-15f;
        float p = scan_incl_mul(ma * mb, lane);
        float T0 = __shfl_up(p, 1, 64);
        if (lane == 0) T0 = 1.0f;
        R.scr[2 * lane]     = aa * T0;
        R.scr[2 * lane + 1] = ab * (T0 * ma);
    }

    // --- wave-parallel CDF over pdf[m]=w[1+m]+1e-5, m=0..125 ---
    {
        float pA = 0.f, pB = 0.f;
        if (lane < 63) {
            pA = R.scr[2 * lane + 1] + 1e-5f;
            pB = R.scr[2 * lane + 2] + 1e-5f;
        }
        float S = scan_incl_add(pA + pB, lane);
        float total = __shfl(S, 63, 64);
        float sexcl = __shfl_up(S, 1, 64);
        if (lane == 0) sexcl = 0.f;
        float inv = 1.0f / total;
        if (lane == 63) {
            R.cdf[0] = 0.0f;
        } else {
            R.cdf[1 + 2 * lane] = (sexcl + pA) * inv;
            R.cdf[2 + 2 * lane] = (sexcl + pA + pB) * inv;
        }
    }

    // --- inverse-CDF sampling ---
#pragma unroll
    for (int bt = 0; bt < 2; ++bt) {
        int i = bt * 64 + lane;
        float u = (float)(2 * i + 1) * (1.0f / 256.0f);
        int lo = 0, hi = 127;
        while (lo < hi) { int mid = (lo + hi) >> 1; if (R.cdf[mid] <= u) lo = mid + 1; else hi = mid; }
        int below = max(lo - 1, 0), above = min(lo, 126);
        float cb = R.cdf[below], ca = R.cdf[above];
        float binb = fmaf(dzc, (float)below + 0.5f, nearv);
        float bina = fmaf(dzc, (float)above + 0.5f, nearv);
        float denom = ca - cb;
        if (denom < 1e-5f) denom = 1.0f;
        float t = (u - cb) / denom;
        R.zf[i] = fmaf(t, bina - binb, binb);
    }

    // --- fine field pass (triple MFMA; cdf/scr free to reuse as stage) ---
    field_pass<false>(R, w1a[0], w1a[1], w1a[2], w1a[3],
                      b00, b01, b10, b11, b20, b21, b30, b31,
                      hda0, hda1, b2q0, b2q1, b2q2, b2q3,
                      ox, oy, oz, dx, dy, dzv, nearv, span, base_r, base_g, base_b, lane);

    // --- stable merge of two sorted length-128 lists ---
#pragma unroll
    for (int bt = 0; bt < 2; ++bt) {
        int k = bt * 64 + lane;
        float v = R.zc[k];
        int lo = 0, hi = 128;
        while (lo < hi) { int mid = (lo + hi) >> 1; if (R.zf[mid] < v) lo = mid + 1; else hi = mid; }
        R.perm[k + lo] = (unsigned short)k;
        float vf = R.zf[k];
        lo = 0; hi = 128;
        while (lo < hi) { int mid = (lo + hi) >> 1; if (R.zc[mid] <= vf) lo = mid + 1; else hi = mid; }
        R.perm[k + lo] = (unsigned short)(128 + k);
    }

    // --- merged composite ---
    {
        int sb = 4 * lane;
        int idxk[4]; float zk[4], sgk[4];
#pragma unroll
        for (int k = 0; k < 4; ++k) {
            int idx = R.perm[sb + k];
            idxk[k] = idx;
            zk[k]  = (idx < 128) ? R.zc[idx]  : R.zf[idx - 128];
            sgk[k] = (idx < 128) ? R.sgc[idx] : R.sgf[idx - 128];
        }
        float znext = __shfl_down(zk[0], 1, 64);
        float d0 = zk[1] - zk[0];
        float d1 = zk[2] - zk[1];
        float d2 = zk[3] - zk[2];
        float d3 = (lane < 63) ? (znext - zk[3]) : sample_dist;
        float a0 = 1.0f - __expf(-d0 * sgk[0]);
        float a1 = 1.0f - __expf(-d1 * sgk[1]);
        float a2 = 1.0f - __expf(-d2 * sgk[2]);
        float a3 = 1.0f - __expf(-d3 * sgk[3]);
        float m0 = 1.0f - a0 + 1e-15f, m1 = 1.0f - a1 + 1e-15f;
        float m2 = 1.0f - a2 + 1e-15f, m3 = 1.0f - a3 + 1e-15f;
        float p = scan_incl_mul((m0 * m1) * (m2 * m3), lane);
        float T = __shfl_up(p, 1, 64);
        if (lane == 0) T = 1.0f;

        const float invspan = 1.0f / span;
        float dacc = 0.f, racc = 0.f, gacc = 0.f, bacc = 0.f, wacc = 0.f;
        float aarr[4] = {a0, a1, a2, a3};
        float marr[4] = {m0, m1, m2, m3};
#pragma unroll
        for (int k = 0; k < 4; ++k) {
            float w = aarr[k] * T;
            float ozv = (zk[k] - nearv) * invspan;
            ozv = (ozv < 0.0f) ? 0.0f : ((ozv > 1.0f) ? 1.0f : ozv);
            dacc = fmaf(w, ozv, dacc);
            const float* rgb = (idxk[k] < 128) ? R.rgbc[idxk[k]] : R.rgbf[idxk[k] - 128];
            racc = fmaf(w, rgb[0], racc);
            gacc = fmaf(w, rgb[1], gacc);
            bacc = fmaf(w, rgb[2], bacc);
            wacc += w;
            T *= marr[k];
        }
#pragma unroll
        for (int off = 32; off; off >>= 1) {
            dacc += __shfl_xor(dacc, off);
            racc += __shfl_xor(racc, off);
            gacc += __shfl_xor(gacc, off);
            bacc += __shfl_xor(bacc, off);
            wacc += __shfl_xor(wacc, off);
        }
        if (lane == 0 && valid) {
            out_depth[ray] = dacc;
            float bg = 1.0f - wacc;
            out_img[ray * 3 + 0] = racc + bg;
            out_img[ray * 3 + 1] = gacc + bg;
            out_img[ray * 3 + 2] = bacc + bg;
        }
    }
}

extern "C" void kernel_launch(void* const* d_in, const int* in_sizes, int n_in,
                              void* d_out, int out_size, void* d_ws, size_t ws_size,
                              hipStream_t stream) {
    const float* rays_o = (const float*)d_in[0];
    const float* rays_d = (const float*)d_in[1];
    const float* W1   = (const float*)d_in[2];
    const float* b1   = (const float*)d_in[3];
    const float* W2   = (const float*)d_in[4];
    const float* b2   = (const float*)d_in[5];
    const float* Wsig = (const float*)d_in[6];
    const float* Wrgb = (const float*)d_in[7];
    const float* brgb = (const float*)d_in[8];

    int N = in_sizes[0] / 3;          // 4096 rays
    float* out = (float*)d_out;
    float* out_depth = out;           // [N]
    float* out_img   = out + N;       // [N,3]

    nerf_kernel<<<dim3(N), dim3(64), 0, stream>>>(
        rays_o, rays_d, W1, b1, W2, b2, Wsig, Wrgb, brgb,
        out_depth, out_img, N);
}